// Round 4
// baseline (134.708 us; speedup 1.0000x reference)
//
#include <hip/hip_runtime.h>
#include <hip/hip_bf16.h>

#define HW 4096  // 64*64 spatial

// Static device scratch (24 MiB): qkv[m][b][o][h][w] fp32, m in {0:q,1:k,2:v}.
// Fully rewritten by qkv_proj before attn reads it on every launch -> graph-safe,
// and avoids any assumption about ws_size.
__device__ float g_qkv[3 * 8 * 64 * HW];

__global__ __launch_bounds__(256) void qkv_proj(
    const float* __restrict__ x,
    const float* __restrict__ wq,
    const float* __restrict__ wk,
    const float* __restrict__ wv)
{
    __shared__ float xs[64][64];      // [c][w]   16 KB
    __shared__ float wl[3][64][64];   // [m][o][c] 48 KB  (total 64 KB -> 2 blocks/CU)

    const int t = threadIdx.x;
    const int b = blockIdx.x >> 6;
    const int h = blockIdx.x & 63;

    const float* mats[3] = { wq, wk, wv };
    for (int i = t; i < 3 * 4096; i += 256) {
        int m = i >> 12, r = i & 4095;
        (&wl[0][0][0])[i] = mats[m][r];   // wl[m][o][c] = w[o*64+c], row-major [O,C]
    }
    {
        const float* xrow = x + (size_t)b * 64 * HW + (size_t)h * 64;
        for (int i = t; i < 64 * 64; i += 256) {
            int c = i >> 6, w = i & 63;
            xs[c][w] = xrow[(size_t)c * HW + w];
        }
    }
    __syncthreads();

    const int w = t & 63;
    const int ou = t >> 6;            // wave-uniform (wave=64)
    float xr[64];
    #pragma unroll
    for (int c = 0; c < 64; ++c) xr[c] = xs[c][w];

    #pragma unroll
    for (int m = 0; m < 3; ++m) {
        float* op = g_qkv + ((size_t)m * 8 + b) * (64 * HW) + (size_t)h * 64 + w;
        #pragma unroll
        for (int oi = 0; oi < 16; ++oi) {
            const int o = oi * 4 + ou;
            float acc = 0.f;
            #pragma unroll
            for (int c = 0; c < 64; ++c)
                acc = fmaf(wl[m][o][c], xr[c], acc);  // wave-uniform wl read -> LDS broadcast
            op[(size_t)o * HW] = acc;
        }
    }
}

// one block per (b,o): 7x7 local attention over a 64x64 image, halo in LDS.
// rel_w/rel_h are dead: constant along the 49-entry softmax axis -> cancel
// (softmax shift-invariance). Zero padding + 1x1 conv => k=v=0 outside; those
// entries' logit is q*0 = 0 and still participates in the softmax.
__global__ __launch_bounds__(256) void attn(float* __restrict__ out)
{
    __shared__ float kt[70][72];
    __shared__ float vt[70][72];
    const int t = threadIdx.x;
    const int b = blockIdx.x >> 6;
    const int o = blockIdx.x & 63;

    const float* qb = g_qkv + ((size_t)(0 * 8 + b) * 64 + o) * HW;
    const float* kb = g_qkv + ((size_t)(1 * 8 + b) * 64 + o) * HW;
    const float* vb = g_qkv + ((size_t)(2 * 8 + b) * 64 + o) * HW;

    for (int i = t; i < 70 * 70; i += 256) {
        int r = i / 70, c = i - r * 70;
        int gh = r - 3, gw = c - 3;
        float kk = 0.f, vv = 0.f;
        if ((unsigned)gh < 64u && (unsigned)gw < 64u) {
            kk = kb[gh * 64 + gw];
            vv = vb[gh * 64 + gw];
        }
        kt[r][c] = kk;
        vt[r][c] = vv;
    }
    __syncthreads();

    const int w = t & 63;
    #pragma unroll 1
    for (int pass = 0; pass < 4; ++pass) {
        const int hbase = (pass * 4 + (t >> 6)) * 4;  // 4 vertically adjacent pixels
        float qv[4];
        float den[4] = {0.f, 0.f, 0.f, 0.f};
        float num[4] = {0.f, 0.f, 0.f, 0.f};
        #pragma unroll
        for (int q = 0; q < 4; ++q) qv[q] = qb[(hbase + q) * 64 + w];

        // union of the 4 pixels' windows: 10 halo rows x 7 cols, each LDS-read once
        #pragma unroll
        for (int rr = 0; rr < 10; ++rr) {
            #pragma unroll
            for (int dj = 0; dj < 7; ++dj) {
                float kk = kt[hbase + rr][w + dj];
                float vv = vt[hbase + rr][w + dj];
                #pragma unroll
                for (int q = 0; q < 4; ++q) {
                    if (rr - q >= 0 && rr - q < 7) {   // compile-time predicate
                        float l = fminf(fmaxf(qv[q] * kk, -60.f), 60.f);  // no-op clamp, NaN insurance
                        float e = __expf(l);
                        den[q] += e;
                        num[q] = fmaf(e, vv, num[q]);
                    }
                }
            }
        }
        #pragma unroll
        for (int q = 0; q < 4; ++q)
            out[((size_t)(b * 64 + o)) * HW + (hbase + q) * 64 + w] = num[q] / den[q];
    }
}

extern "C" void kernel_launch(void* const* d_in, const int* in_sizes, int n_in,
                              void* d_out, int out_size, void* d_ws, size_t ws_size,
                              hipStream_t stream)
{
    // d_in: 0=x, 1=wq, 2=wk, 3=wv (all fp32), 4=rel_w, 5=rel_h (dead: softmax
    // shift-invariance), 6=kernel_size(7), 7=padding(3) hardcoded.
    qkv_proj<<<dim3(512), dim3(256), 0, stream>>>(
        (const float*)d_in[0], (const float*)d_in[1],
        (const float*)d_in[2], (const float*)d_in[3]);
    attn<<<dim3(512), dim3(256), 0, stream>>>((float*)d_out);  // fp32 output per reference dtype
}